// Round 4
// baseline (105.331 us; speedup 1.0000x reference)
//
#include <hip/hip_runtime.h>
#include <math.h>

// WavefunctionEmbedding, histogram-factorized:
//   out[b,i,2k+0/1] = sum_j amp_ij * {cos,sin}(wn_k * r_ij)
// Scatter amp into a per-row radial histogram (cubic Lagrange deposit onto
// Q=256 nodes, int32 fixed-point LDS atomics), then contract with a
// [QG, 2K] cos/sin table: out = H x W. Trans ops: 2.4e9 -> 1.3e5.
//
// R4 changes vs R3 (98 us):
//  - Pipeline 4 kernels -> 2. scale+table folded into hist: every hist block
//    redundantly computes rmax (deterministic identical reduction -> identical
//    h in all blocks); blocks 0..QG-1 also write their W table row.
//  - gemm: R3 version was LDS-pipe-bound (1584 ds_read_b32 broadcasts/wave,
//    ~5.8cyc each through the one per-CU LDS pipe). New gemm uses NO LDS:
//    H loads are wave-uniform float4 (-> s_load_dwordx4 scalar-cache path),
//    W streams from L2 as per-thread float2. RT=12 -> 256 blocks = 1/CU,
//    W traffic 138 MB (~4 us of L2 BW), 24 independent FMA chains for ILP.

#define N_FIXED 1536
#define K_FIXED 256
#define QBINS   256
#define QG      (QBINS + 4)     // node a represents r = (a-1)*h; ghosts at ends
#define RT      12              // rows per GEMM block (256 blocks * 12 = 3072)
#define FPSCALE 4194304.0f      // 2^22 fixed-point scale for hist deposits

// ---------------- fallback: direct kernel (round-1, known-good) ------------
__global__ __launch_bounds__(256) void wf_direct_kernel(
    const float* __restrict__ coords, const unsigned char* __restrict__ mask,
    const float* __restrict__ wavenumbers, float* __restrict__ out, int N, int K)
{
    __shared__ float2 pairs[N_FIXED];
    const int row = blockIdx.x;
    const int b   = row / N;
    const int i   = row - b * N;
    const int t   = threadIdx.x;
    const float* crow = coords + (size_t)b * N * 3;
    const float xi = crow[i*3+0], yi = crow[i*3+1], zi = crow[i*3+2];
    const unsigned char* mrow = mask + (size_t)b * N;
    for (int j = t; j < N; j += blockDim.x) {
        float dx = crow[j*3+0]-xi, dy = crow[j*3+1]-yi, dz = crow[j*3+2]-zi;
        float d2 = fmaf(dx,dx, fmaf(dy,dy, fmaf(dz,dz, 1e-12f)));
        float r  = sqrtf(d2);
        float amp = 0.07957747154594767f / fmaxf(r, 1e-6f);
        if (j == i || mrow[j]) amp = 0.0f;
        pairs[j] = make_float2(r, amp);
    }
    __syncthreads();
    const int k = t;
    const float f = wavenumbers[k] * 0.15915494309189535f;
    float re = 0.0f, im = 0.0f;
    #pragma unroll 4
    for (int j = 0; j < N; ++j) {
        float2 p = pairs[j];
        float x  = __builtin_amdgcn_fractf(p.x * f);
        float c  = __builtin_amdgcn_cosf(x);
        float s  = __builtin_amdgcn_sinf(x);
        re = fmaf(c, p.y, re);
        im = fmaf(s, p.y, im);
    }
    float2* orow = (float2*)out + (size_t)row * K;
    orow[k] = make_float2(re, im);
}

// ---- k1: per-row radial histogram + redundant rmax + W-table rows ---------
__global__ __launch_bounds__(256) void wf_hist_kernel(
    const float* __restrict__ coords, const unsigned char* __restrict__ mask,
    const float* __restrict__ wavenumbers,
    float* __restrict__ W, float* __restrict__ H, int n_pts, int N)
{
    __shared__ int   hist[QG];             // ~1 KB
    __shared__ float red[4];

    const int row = blockIdx.x;
    const int b   = row / N;
    const int i   = row - b * N;
    const int t   = threadIdx.x;

    // ---- redundant rmax over ALL points (identical in every block ->
    //      identical h; exact same arithmetic as the old wf_scale_kernel) ----
    float m = 0.0f;
    for (int p = t; p < n_pts; p += 256) {
        float x = coords[3*p], y = coords[3*p+1], z = coords[3*p+2];
        m = fmaxf(m, fmaf(x,x, fmaf(y,y, z*z)));
    }
    #pragma unroll
    for (int off = 32; off >= 1; off >>= 1)
        m = fmaxf(m, __shfl_down(m, off, 64));
    if ((t & 63) == 0) red[t >> 6] = m;
    for (int a = t; a < QG; a += 256) hist[a] = 0;
    __syncthreads();
    const float mm   = fmaxf(fmaxf(red[0], red[1]), fmaxf(red[2], red[3]));
    const float rmax = 2.0005f * sqrtf(mm) + 1e-3f;   // r_ij <= 2 max|c|
    const float h    = rmax / (float)QBINS;
    const float inv_h = 1.0f / h;

    // ---- blocks 0..QG-1 also emit one W table row: r_node = (row-1)*h ----
    if (row < QG) {
        const float rn = ((float)row - 1.0f) * h;
        const float f  = wavenumbers[t] * 0.15915494309189535f;
        float x = __builtin_amdgcn_fractf(f * rn);
        float2* Wrow = (float2*)(W + (size_t)row * 2 * K_FIXED);
        Wrow[t] = make_float2(__builtin_amdgcn_cosf(x), __builtin_amdgcn_sinf(x));
    }

    // ---- histogram (int fixed-point, native ds_add) ----
    const float* crow = coords + (size_t)b * N * 3;
    const unsigned char* mrow = mask + (size_t)b * N;
    const float xi = crow[3*i], yi = crow[3*i+1], zi = crow[3*i+2];

    #pragma unroll
    for (int s = 0; s < N_FIXED / 256; ++s) {
        int j = t + 256 * s;
        float dx = crow[3*j]   - xi;
        float dy = crow[3*j+1] - yi;
        float dz = crow[3*j+2] - zi;
        float d2 = fmaf(dx,dx, fmaf(dy,dy, fmaf(dz,dz, 1e-12f)));
        float r  = sqrtf(d2);
        float amp = 0.07957747154594767f / fmaxf(r, 1e-6f);
        if (j == i || mrow[j]) amp = 0.0f;

        float u  = r * inv_h;
        float qf = floorf(u);
        int   q0 = (int)qf;
        q0 = q0 < 0 ? 0 : (q0 > QBINS ? QBINS : q0);
        float tt = u - qf;
        // Lagrange cubic through nodes {-1,0,1,2} at offset tt in [0,1)
        float as  = amp * FPSCALE;
        float tm1 = tt + 1.0f, t1 = tt - 1.0f, t2 = tt - 2.0f;
        float w0 = -tt * t1 * t2 * (1.0f/6.0f) * as;
        float w1 =  tm1 * t1 * t2 * 0.5f * as;
        float w2 = -tm1 * tt * t2 * 0.5f * as;
        float w3 =  tm1 * tt * t1 * (1.0f/6.0f) * as;
        atomicAdd(&hist[q0    ], __float2int_rn(w0));   // native ds_add_u32
        atomicAdd(&hist[q0 + 1], __float2int_rn(w1));
        atomicAdd(&hist[q0 + 2], __float2int_rn(w2));
        atomicAdd(&hist[q0 + 3], __float2int_rn(w3));
    }
    __syncthreads();

    float* Hrow = H + (size_t)row * QG;
    const float invS = 1.0f / FPSCALE;
    for (int a = t; a < QG; a += 256) Hrow[a] = (float)hist[a] * invS;
}

// ---- k2: out = H x W, no LDS: uniform H -> scalar cache, W from L2 --------
__global__ __launch_bounds__(256) void wf_gemm_kernel(
    const float* __restrict__ H, const float* __restrict__ W,
    float* __restrict__ out)
{
    const int i0 = blockIdx.x * RT;
    const int t  = threadIdx.x;            // k-pair index

    float2 acc[RT];
    #pragma unroll
    for (int r = 0; r < RT; ++r) acc[r] = make_float2(0.0f, 0.0f);

    const float2* __restrict__ W2 = (const float2*)W;   // [QG][K_FIXED]

    #pragma unroll 1
    for (int q0 = 0; q0 < QG; q0 += 4) {                // QG=260 -> 65 iters
        float2 w0 = W2[(size_t)(q0+0) * K_FIXED + t];
        float2 w1 = W2[(size_t)(q0+1) * K_FIXED + t];
        float2 w2 = W2[(size_t)(q0+2) * K_FIXED + t];
        float2 w3 = W2[(size_t)(q0+3) * K_FIXED + t];
        #pragma unroll
        for (int r = 0; r < RT; ++r) {
            // wave-uniform aligned float4 load (row stride 260*4B = 16B mult)
            const float4 h4 = *(const float4*)&H[(size_t)(i0 + r) * QG + q0];
            acc[r].x = fmaf(h4.x, w0.x, acc[r].x); acc[r].y = fmaf(h4.x, w0.y, acc[r].y);
            acc[r].x = fmaf(h4.y, w1.x, acc[r].x); acc[r].y = fmaf(h4.y, w1.y, acc[r].y);
            acc[r].x = fmaf(h4.z, w2.x, acc[r].x); acc[r].y = fmaf(h4.z, w2.y, acc[r].y);
            acc[r].x = fmaf(h4.w, w3.x, acc[r].x); acc[r].y = fmaf(h4.w, w3.y, acc[r].y);
        }
    }

    #pragma unroll
    for (int r = 0; r < RT; ++r)
        ((float2*)out)[(size_t)(i0 + r) * K_FIXED + t] = acc[r];
}

extern "C" void kernel_launch(void* const* d_in, const int* in_sizes, int n_in,
                              void* d_out, int out_size, void* d_ws, size_t ws_size,
                              hipStream_t stream) {
    const float* coords          = (const float*)d_in[0];
    const unsigned char* mask    = (const unsigned char*)d_in[1];
    const float* wavenumbers     = (const float*)d_in[2];
    float* out                   = (float*)d_out;

    const int K  = in_sizes[2];
    const int BN = in_sizes[0] / 3;        // B*N
    const int N  = N_FIXED;

    // ws layout (floats): W (QG*2K) | H (BN*QG)
    const size_t H_off = (size_t)QG * 2 * K_FIXED;
    const size_t need  = (H_off + (size_t)BN * QG) * sizeof(float);

    if (K != K_FIXED || BN % N != 0 || (BN % RT) != 0 || BN < QG ||
        ws_size < need) {
        wf_direct_kernel<<<BN, K, 0, stream>>>(coords, mask, wavenumbers, out, N, K);
        return;
    }

    float* W = (float*)d_ws;
    float* H = W + H_off;

    wf_hist_kernel<<<BN, 256, 0, stream>>>(coords, mask, wavenumbers, W, H, BN, N);
    wf_gemm_kernel<<<BN / RT, 256, 0, stream>>>(H, W, out);
}

// Round 5
// 102.271 us; speedup vs baseline: 1.0299x; 1.0299x over previous
//
#include <hip/hip_runtime.h>
#include <math.h>

// WavefunctionEmbedding, histogram-factorized:
//   out[b,i,2k+0/1] = sum_j amp_ij * {cos,sin}(wn_k * r_ij)
// Scatter amp into per-row radial histograms (cubic Lagrange deposit onto
// Q=256 nodes, int32 fixed-point LDS atomics), then contract with a
// [QG, 2K] cos/sin table: out = H x W. Trans ops: 2.4e9 -> 1.3e5.
//
// R5 changes vs R4 (105 us):
//  - gemm: R4 ran 256 blocks x 256 thr = 1 wave/SIMD -> L2 latency exposed.
//    Now thread owns ONE output float (col 0..511), RT=12 rows, grid
//    256 x 512 thr = 2 waves/SIMD at the SAME minimal W traffic (136 MB).
//    12 independent FMA chains/thread; H via wave-uniform float4 loads.
//  - hist: ROWS=4 rows/block (768 blocks = 3/CU exactly). Redundant rmax
//    traffic /4; j-coords+mask loaded once per j, reused for all 4 rows;
//    LDS just 4 int histograms (4.2 KB). Deposit math bit-identical to R4.

#define N_FIXED 1536
#define K_FIXED 256
#define QBINS   256
#define QG      (QBINS + 4)     // node a represents r = (a-1)*h; ghosts at ends
#define ROWS    4               // hist rows per block
#define RT      12              // gemm rows per block
#define FPSCALE 4194304.0f      // 2^22 fixed-point scale for hist deposits

// ---------------- fallback: direct kernel (round-1, known-good) ------------
__global__ __launch_bounds__(256) void wf_direct_kernel(
    const float* __restrict__ coords, const unsigned char* __restrict__ mask,
    const float* __restrict__ wavenumbers, float* __restrict__ out, int N, int K)
{
    __shared__ float2 pairs[N_FIXED];
    const int row = blockIdx.x;
    const int b   = row / N;
    const int i   = row - b * N;
    const int t   = threadIdx.x;
    const float* crow = coords + (size_t)b * N * 3;
    const float xi = crow[i*3+0], yi = crow[i*3+1], zi = crow[i*3+2];
    const unsigned char* mrow = mask + (size_t)b * N;
    for (int j = t; j < N; j += blockDim.x) {
        float dx = crow[j*3+0]-xi, dy = crow[j*3+1]-yi, dz = crow[j*3+2]-zi;
        float d2 = fmaf(dx,dx, fmaf(dy,dy, fmaf(dz,dz, 1e-12f)));
        float r  = sqrtf(d2);
        float amp = 0.07957747154594767f / fmaxf(r, 1e-6f);
        if (j == i || mrow[j]) amp = 0.0f;
        pairs[j] = make_float2(r, amp);
    }
    __syncthreads();
    const int k = t;
    const float f = wavenumbers[k] * 0.15915494309189535f;
    float re = 0.0f, im = 0.0f;
    #pragma unroll 4
    for (int j = 0; j < N; ++j) {
        float2 p = pairs[j];
        float x  = __builtin_amdgcn_fractf(p.x * f);
        float c  = __builtin_amdgcn_cosf(x);
        float s  = __builtin_amdgcn_sinf(x);
        re = fmaf(c, p.y, re);
        im = fmaf(s, p.y, im);
    }
    float2* orow = (float2*)out + (size_t)row * K;
    orow[k] = make_float2(re, im);
}

// ---- k1: 4-row radial histograms + redundant rmax + W-table rows ----------
__global__ __launch_bounds__(256) void wf_hist_kernel(
    const float* __restrict__ coords, const unsigned char* __restrict__ mask,
    const float* __restrict__ wavenumbers,
    float* __restrict__ W, float* __restrict__ H, int n_pts, int N)
{
    __shared__ int   hist[ROWS * QG];      // 4.2 KB
    __shared__ float red[4];

    const int i0 = blockIdx.x * ROWS;      // first global row of this block
    const int b  = i0 / N;                 // N % ROWS == 0 -> whole block in b
    const int t  = threadIdx.x;

    // ---- redundant rmax over ALL points (identical reduction in every
    //      block -> identical h; same arithmetic as R3/R4) ----
    float m = 0.0f;
    for (int p = t; p < n_pts; p += 256) {
        float x = coords[3*p], y = coords[3*p+1], z = coords[3*p+2];
        m = fmaxf(m, fmaf(x,x, fmaf(y,y, z*z)));
    }
    #pragma unroll
    for (int off = 32; off >= 1; off >>= 1)
        m = fmaxf(m, __shfl_down(m, off, 64));
    if ((t & 63) == 0) red[t >> 6] = m;
    for (int a = t; a < ROWS * QG; a += 256) hist[a] = 0;
    __syncthreads();
    const float mm   = fmaxf(fmaxf(red[0], red[1]), fmaxf(red[2], red[3]));
    const float rmax = 2.0005f * sqrtf(mm) + 1e-3f;   // r_ij <= 2 max|c|
    const float h    = rmax / (float)QBINS;
    const float inv_h = 1.0f / h;

    // ---- blocks 0..QG-1 also emit one W table row: r_node = (blk-1)*h ----
    if (blockIdx.x < QG) {
        const float rn = ((float)blockIdx.x - 1.0f) * h;
        const float f  = wavenumbers[t] * 0.15915494309189535f;
        float x = __builtin_amdgcn_fractf(f * rn);
        float2* Wrow = (float2*)(W + (size_t)blockIdx.x * 2 * K_FIXED);
        Wrow[t] = make_float2(__builtin_amdgcn_cosf(x), __builtin_amdgcn_sinf(x));
    }

    // ---- histograms: load each j once, deposit into all ROWS rows ----
    const float* crow = coords + (size_t)b * N * 3;
    const unsigned char* mrow = mask + (size_t)b * N;
    const int il0 = i0 - b * N;            // local i of row 0

    float cx[ROWS], cy[ROWS], cz[ROWS];
    #pragma unroll
    for (int r = 0; r < ROWS; ++r) {
        cx[r] = crow[3*(il0+r)];
        cy[r] = crow[3*(il0+r)+1];
        cz[r] = crow[3*(il0+r)+2];
    }

    #pragma unroll
    for (int s = 0; s < N_FIXED / 256; ++s) {
        const int j = t + 256 * s;
        const float xj = crow[3*j], yj = crow[3*j+1], zj = crow[3*j+2];
        const bool masked = (mrow[j] != 0);
        #pragma unroll
        for (int r = 0; r < ROWS; ++r) {
            float dx = xj - cx[r];
            float dy = yj - cy[r];
            float dz = zj - cz[r];
            float d2 = fmaf(dx,dx, fmaf(dy,dy, fmaf(dz,dz, 1e-12f)));
            float rr = sqrtf(d2);
            float amp = 0.07957747154594767f / fmaxf(rr, 1e-6f);
            if (j == il0 + r || masked) amp = 0.0f;

            float u  = rr * inv_h;
            float qf = floorf(u);
            int   q0 = (int)qf;
            q0 = q0 < 0 ? 0 : (q0 > QBINS ? QBINS : q0);
            float tt = u - qf;
            // Lagrange cubic through nodes {-1,0,1,2} at offset tt in [0,1)
            float as  = amp * FPSCALE;
            float tm1 = tt + 1.0f, t1 = tt - 1.0f, t2 = tt - 2.0f;
            float w0 = -tt * t1 * t2 * (1.0f/6.0f) * as;
            float w1 =  tm1 * t1 * t2 * 0.5f * as;
            float w2 = -tm1 * tt * t2 * 0.5f * as;
            float w3 =  tm1 * tt * t1 * (1.0f/6.0f) * as;
            int* hb = &hist[r * QG + q0];
            atomicAdd(hb    , __float2int_rn(w0));   // native ds_add_u32
            atomicAdd(hb + 1, __float2int_rn(w1));
            atomicAdd(hb + 2, __float2int_rn(w2));
            atomicAdd(hb + 3, __float2int_rn(w3));
        }
    }
    __syncthreads();

    float* Hrow = H + (size_t)i0 * QG;
    const float invS = 1.0f / FPSCALE;
    for (int a = t; a < ROWS * QG; a += 256) Hrow[a] = (float)hist[a] * invS;
}

// ---- k2: out = H x W; thread owns one output float; 2 waves/SIMD ----------
__global__ __launch_bounds__(512) void wf_gemm_kernel(
    const float* __restrict__ H, const float* __restrict__ W,
    float* __restrict__ out)
{
    const int i0 = blockIdx.x * RT;
    const int c  = threadIdx.x;            // column 0..511 (interleaved re/im)

    float acc[RT];
    #pragma unroll
    for (int r = 0; r < RT; ++r) acc[r] = 0.0f;

    #pragma unroll 1
    for (int q0 = 0; q0 < QG; q0 += 4) {                // 65 iters
        float w0 = W[(size_t)(q0+0) * (2*K_FIXED) + c]; // coalesced b32
        float w1 = W[(size_t)(q0+1) * (2*K_FIXED) + c];
        float w2 = W[(size_t)(q0+2) * (2*K_FIXED) + c];
        float w3 = W[(size_t)(q0+3) * (2*K_FIXED) + c];
        #pragma unroll
        for (int r = 0; r < RT; ++r) {
            // wave-uniform aligned float4 (H row stride 1040 B, 16B mult)
            const float4 h4 = *(const float4*)&H[(size_t)(i0 + r) * QG + q0];
            acc[r] = fmaf(h4.x, w0, acc[r]);
            acc[r] = fmaf(h4.y, w1, acc[r]);
            acc[r] = fmaf(h4.z, w2, acc[r]);
            acc[r] = fmaf(h4.w, w3, acc[r]);
        }
    }

    #pragma unroll
    for (int r = 0; r < RT; ++r)
        out[(size_t)(i0 + r) * (2*K_FIXED) + c] = acc[r];
}

extern "C" void kernel_launch(void* const* d_in, const int* in_sizes, int n_in,
                              void* d_out, int out_size, void* d_ws, size_t ws_size,
                              hipStream_t stream) {
    const float* coords          = (const float*)d_in[0];
    const unsigned char* mask    = (const unsigned char*)d_in[1];
    const float* wavenumbers     = (const float*)d_in[2];
    float* out                   = (float*)d_out;

    const int K  = in_sizes[2];
    const int BN = in_sizes[0] / 3;        // B*N
    const int N  = N_FIXED;

    // ws layout (floats): W (QG*2K) | H (BN*QG)
    const size_t H_off = (size_t)QG * 2 * K_FIXED;
    const size_t need  = (H_off + (size_t)BN * QG) * sizeof(float);

    if (K != K_FIXED || BN % N != 0 || (N % ROWS) != 0 || (BN % RT) != 0 ||
        BN / ROWS < QG || ws_size < need) {
        wf_direct_kernel<<<BN, K, 0, stream>>>(coords, mask, wavenumbers, out, N, K);
        return;
    }

    float* W = (float*)d_ws;
    float* H = W + H_off;

    wf_hist_kernel<<<BN / ROWS, 256, 0, stream>>>(coords, mask, wavenumbers, W, H, BN, N);
    wf_gemm_kernel<<<BN / RT, 512, 0, stream>>>(H, W, out);
}

// Round 6
// 96.444 us; speedup vs baseline: 1.0921x; 1.0604x over previous
//
#include <hip/hip_runtime.h>
#include <math.h>

// WavefunctionEmbedding, fully fused single kernel (NO workspace):
//   out[b,i,2k+0/1] = sum_j amp_ij * {cos,sin}(wn_k * r_ij)
// Each block owns ROWS=4 rows: builds their radial histograms in LDS
// (cubic Lagrange deposit, int32 fixed-point ds_add), then contracts them
// IN-BLOCK against cos/sin(wn_k * r_q) generated by a per-thread rotation
// recurrence (4 FMA/step) -- no W table, no H round-trip, no second kernel,
// no d_ws dependency (harness ws poison can overlap / drop off critical path).
//
// R6 rationale vs R5 (102 us): R4/R5 kernel tweaks moved nothing; suspected
// cost is the ws-poison -> kernel dependency + inter-kernel gaps. This
// version touches ONLY d_in and d_out.
//
// Phase 2 structure: wave w = row w of the block; lane owns 4 col-pairs
// k = lane + 64j; per q: 1 broadcast ds_read_b32 + 8 acc FMA + 16 rot FMA.
// Rotation seeds from hw cos/sin (input in revolutions, wn*h/2pi < 0.08).
// 260-step drift ~1.5e-5 -- negligible vs 0.031 current absmax.

#define N_FIXED 1536
#define K_FIXED 256
#define QBINS   256
#define QG      (QBINS + 4)     // node a represents r = (a-1)*h
#define ROWS    4               // rows per block (768 blocks = 3/CU exactly)
#define FPSCALE 4194304.0f      // 2^22 fixed-point scale for hist deposits

// ---------------- fallback: direct kernel (round-1, known-good) ------------
__global__ __launch_bounds__(256) void wf_direct_kernel(
    const float* __restrict__ coords, const unsigned char* __restrict__ mask,
    const float* __restrict__ wavenumbers, float* __restrict__ out, int N, int K)
{
    __shared__ float2 pairs[N_FIXED];
    const int row = blockIdx.x;
    const int b   = row / N;
    const int i   = row - b * N;
    const int t   = threadIdx.x;
    const float* crow = coords + (size_t)b * N * 3;
    const float xi = crow[i*3+0], yi = crow[i*3+1], zi = crow[i*3+2];
    const unsigned char* mrow = mask + (size_t)b * N;
    for (int j = t; j < N; j += blockDim.x) {
        float dx = crow[j*3+0]-xi, dy = crow[j*3+1]-yi, dz = crow[j*3+2]-zi;
        float d2 = fmaf(dx,dx, fmaf(dy,dy, fmaf(dz,dz, 1e-12f)));
        float r  = sqrtf(d2);
        float amp = 0.07957747154594767f / fmaxf(r, 1e-6f);
        if (j == i || mrow[j]) amp = 0.0f;
        pairs[j] = make_float2(r, amp);
    }
    __syncthreads();
    const int k = t;
    const float f = wavenumbers[k] * 0.15915494309189535f;
    float re = 0.0f, im = 0.0f;
    #pragma unroll 4
    for (int j = 0; j < N; ++j) {
        float2 p = pairs[j];
        float x  = __builtin_amdgcn_fractf(p.x * f);
        float c  = __builtin_amdgcn_cosf(x);
        float s  = __builtin_amdgcn_sinf(x);
        re = fmaf(c, p.y, re);
        im = fmaf(s, p.y, im);
    }
    float2* orow = (float2*)out + (size_t)row * K;
    orow[k] = make_float2(re, im);
}

// ---------------- fused: hist + in-block contraction -----------------------
__global__ __launch_bounds__(256) void wf_fused_kernel(
    const float* __restrict__ coords, const unsigned char* __restrict__ mask,
    const float* __restrict__ wavenumbers, float* __restrict__ out,
    int n_pts, int N)
{
    __shared__ int   hist[ROWS * QG];      // 4.2 KB; reused as float after cvt
    __shared__ float red[4];

    const int i0 = blockIdx.x * ROWS;      // first global row of this block
    const int b  = i0 / N;                 // N % ROWS == 0 -> block within b
    const int t  = threadIdx.x;

    // ---- redundant rmax over ALL points (identical reduction in every
    //      block -> identical h; same arithmetic as R3/R4/R5) ----
    float m = 0.0f;
    for (int p = t; p < n_pts; p += 256) {
        float x = coords[3*p], y = coords[3*p+1], z = coords[3*p+2];
        m = fmaxf(m, fmaf(x,x, fmaf(y,y, z*z)));
    }
    #pragma unroll
    for (int off = 32; off >= 1; off >>= 1)
        m = fmaxf(m, __shfl_down(m, off, 64));
    if ((t & 63) == 0) red[t >> 6] = m;
    for (int a = t; a < ROWS * QG; a += 256) hist[a] = 0;
    __syncthreads();
    const float mm   = fmaxf(fmaxf(red[0], red[1]), fmaxf(red[2], red[3]));
    const float rmax = 2.0005f * sqrtf(mm) + 1e-3f;   // r_ij <= 2 max|c|
    const float h    = rmax / (float)QBINS;
    const float inv_h = 1.0f / h;

    // ---- histograms: load each j once, deposit into all ROWS rows ----
    const float* crow = coords + (size_t)b * N * 3;
    const unsigned char* mrow = mask + (size_t)b * N;
    const int il0 = i0 - b * N;            // local i of row 0

    float cx[ROWS], cy[ROWS], cz[ROWS];
    #pragma unroll
    for (int r = 0; r < ROWS; ++r) {
        cx[r] = crow[3*(il0+r)];
        cy[r] = crow[3*(il0+r)+1];
        cz[r] = crow[3*(il0+r)+2];
    }

    #pragma unroll
    for (int s = 0; s < N_FIXED / 256; ++s) {
        const int j = t + 256 * s;
        const float xj = crow[3*j], yj = crow[3*j+1], zj = crow[3*j+2];
        const bool masked = (mrow[j] != 0);
        #pragma unroll
        for (int r = 0; r < ROWS; ++r) {
            float dx = xj - cx[r];
            float dy = yj - cy[r];
            float dz = zj - cz[r];
            float d2 = fmaf(dx,dx, fmaf(dy,dy, fmaf(dz,dz, 1e-12f)));
            float rr = sqrtf(d2);
            float amp = 0.07957747154594767f / fmaxf(rr, 1e-6f);
            if (j == il0 + r || masked) amp = 0.0f;

            float u  = rr * inv_h;
            float qf = floorf(u);
            int   q0 = (int)qf;
            q0 = q0 < 0 ? 0 : (q0 > QBINS ? QBINS : q0);
            float tt = u - qf;
            // Lagrange cubic through nodes {-1,0,1,2} at offset tt in [0,1)
            float as  = amp * FPSCALE;
            float tm1 = tt + 1.0f, t1 = tt - 1.0f, t2 = tt - 2.0f;
            float w0 = -tt * t1 * t2 * (1.0f/6.0f) * as;
            float w1 =  tm1 * t1 * t2 * 0.5f * as;
            float w2 = -tm1 * tt * t2 * 0.5f * as;
            float w3 =  tm1 * tt * t1 * (1.0f/6.0f) * as;
            int* hb = &hist[r * QG + q0];
            atomicAdd(hb    , __float2int_rn(w0));   // native ds_add_u32
            atomicAdd(hb + 1, __float2int_rn(w1));
            atomicAdd(hb + 2, __float2int_rn(w2));
            atomicAdd(hb + 3, __float2int_rn(w3));
        }
    }
    __syncthreads();

    // ---- convert int -> float in place (each slot touched by one thread) --
    float* hf = (float*)hist;
    const float invS = 1.0f / FPSCALE;
    for (int a = t; a < ROWS * QG; a += 256) hf[a] = (float)hist[a] * invS;
    __syncthreads();

    // ---- in-block contraction: wave w = row w; lane owns 4 col-pairs ------
    const int w    = t >> 6;               // 0..3
    const int lane = t & 63;
    const float* hrow = hf + w * QG;

    float cs[4], sn[4], cr[4], si[4], are[4], aim[4];
    #pragma unroll
    for (int j = 0; j < 4; ++j) {
        const int k = lane + 64 * j;
        // step angle theta_k = wn_k * h; hw trans takes revolutions (<0.08)
        const float xrev = wavenumbers[k] * 0.15915494309189535f * h;
        const float c1 = __builtin_amdgcn_cosf(xrev);
        const float s1 = __builtin_amdgcn_sinf(xrev);
        cs[j] = c1;  sn[j] = s1;
        cr[j] = c1;  si[j] = -s1;          // node q=0 is r=-h -> angle -theta
        are[j] = 0.0f; aim[j] = 0.0f;
    }

    #pragma unroll 2
    for (int q = 0; q < QG; ++q) {
        const float hv = hrow[q];          // broadcast ds_read_b32
        #pragma unroll
        for (int j = 0; j < 4; ++j) {
            are[j] = fmaf(hv, cr[j], are[j]);
            aim[j] = fmaf(hv, si[j], aim[j]);
            const float cn = fmaf(cr[j], cs[j], -(si[j] * sn[j]));
            const float s2 = fmaf(si[j], cs[j],  (cr[j] * sn[j]));
            cr[j] = cn; si[j] = s2;
        }
    }

    float2* orow = (float2*)(out + (size_t)(i0 + w) * 2 * K_FIXED);
    #pragma unroll
    for (int j = 0; j < 4; ++j)
        orow[lane + 64 * j] = make_float2(are[j], aim[j]);
}

extern "C" void kernel_launch(void* const* d_in, const int* in_sizes, int n_in,
                              void* d_out, int out_size, void* d_ws, size_t ws_size,
                              hipStream_t stream) {
    const float* coords          = (const float*)d_in[0];
    const unsigned char* mask    = (const unsigned char*)d_in[1];
    const float* wavenumbers     = (const float*)d_in[2];
    float* out                   = (float*)d_out;

    const int K  = in_sizes[2];
    const int BN = in_sizes[0] / 3;        // B*N
    const int N  = N_FIXED;

    if (K != K_FIXED || BN % N != 0 || (N % ROWS) != 0) {
        wf_direct_kernel<<<BN, K, 0, stream>>>(coords, mask, wavenumbers, out, N, K);
        return;
    }

    wf_fused_kernel<<<BN / ROWS, 256, 0, stream>>>(coords, mask, wavenumbers,
                                                   out, BN, N);
}

// Round 7
// 83.687 us; speedup vs baseline: 1.2586x; 1.1524x over previous
//
#include <hip/hip_runtime.h>
#include <math.h>

// WavefunctionEmbedding, fully fused single kernel (NO workspace):
//   out[b,i,2k+0/1] = sum_j amp_ij * {cos,sin}(wn_k * r_ij)
// Each block owns ROWS=4 rows: builds their radial histograms in LDS
// (cubic Lagrange deposit, int32 fixed-point ds_add), then contracts them
// in-block against cos/sin(wn_k * r_q) generated by a per-thread rotation
// recurrence. No d_ws dependency (the harness's 42 us ws re-poison fill is a
// fixed serialized cost; our kernel is the only other term).
//
// R7 changes vs R6 (kernel 49 us, VALUBusy 72% -- VALU-issue-bound):
//  - R6 contraction: wave=row, lane=4 col-pairs -> per (thread,q) 16 rot FMA
//    + 8 acc FMA, and the SAME table rotation redone in each of 4 waves.
//  - R7: thread owns ONE col-pair (k = t) for ALL 4 rows -> per (thread,q)
//    4 rot FMA (shared) + 8 acc FMA = 12 vs 24. 2x fewer VALU instrs.
//  - hist stored interleaved (q,r) -> q*5+r (stride 5 coprime to 32 banks:
//    deposit conflict profile unchanged); contraction reads 4 same-address
//    broadcast ds_read_b32 per q (conflict-free).
// Deposit math / h / rotation math bit-identical to R6 -> same absmax.

#define N_FIXED 1536
#define K_FIXED 256
#define QBINS   256
#define QG      (QBINS + 4)     // node a represents r = (a-1)*h
#define ROWS    4               // rows per block (768 blocks = 3/CU exactly)
#define HSTRIDE 5               // interleaved hist stride (coprime to 32)
#define FPSCALE 4194304.0f      // 2^22 fixed-point scale for hist deposits

// ---------------- fallback: direct kernel (round-1, known-good) ------------
__global__ __launch_bounds__(256) void wf_direct_kernel(
    const float* __restrict__ coords, const unsigned char* __restrict__ mask,
    const float* __restrict__ wavenumbers, float* __restrict__ out, int N, int K)
{
    __shared__ float2 pairs[N_FIXED];
    const int row = blockIdx.x;
    const int b   = row / N;
    const int i   = row - b * N;
    const int t   = threadIdx.x;
    const float* crow = coords + (size_t)b * N * 3;
    const float xi = crow[i*3+0], yi = crow[i*3+1], zi = crow[i*3+2];
    const unsigned char* mrow = mask + (size_t)b * N;
    for (int j = t; j < N; j += blockDim.x) {
        float dx = crow[j*3+0]-xi, dy = crow[j*3+1]-yi, dz = crow[j*3+2]-zi;
        float d2 = fmaf(dx,dx, fmaf(dy,dy, fmaf(dz,dz, 1e-12f)));
        float r  = sqrtf(d2);
        float amp = 0.07957747154594767f / fmaxf(r, 1e-6f);
        if (j == i || mrow[j]) amp = 0.0f;
        pairs[j] = make_float2(r, amp);
    }
    __syncthreads();
    const int k = t;
    const float f = wavenumbers[k] * 0.15915494309189535f;
    float re = 0.0f, im = 0.0f;
    #pragma unroll 4
    for (int j = 0; j < N; ++j) {
        float2 p = pairs[j];
        float x  = __builtin_amdgcn_fractf(p.x * f);
        float c  = __builtin_amdgcn_cosf(x);
        float s  = __builtin_amdgcn_sinf(x);
        re = fmaf(c, p.y, re);
        im = fmaf(s, p.y, im);
    }
    float2* orow = (float2*)out + (size_t)row * K;
    orow[k] = make_float2(re, im);
}

// ---------------- fused: hist + in-block contraction -----------------------
__global__ __launch_bounds__(256) void wf_fused_kernel(
    const float* __restrict__ coords, const unsigned char* __restrict__ mask,
    const float* __restrict__ wavenumbers, float* __restrict__ out,
    int n_pts, int N)
{
    __shared__ int   hist[HSTRIDE * QG];   // 5.2 KB; (q,r) at q*5+r
    __shared__ float red[4];

    const int i0 = blockIdx.x * ROWS;      // first global row of this block
    const int b  = i0 / N;                 // N % ROWS == 0 -> block within b
    const int t  = threadIdx.x;

    // ---- redundant rmax over ALL points (identical reduction in every
    //      block -> identical h; same arithmetic as R3..R6) ----
    float m = 0.0f;
    for (int p = t; p < n_pts; p += 256) {
        float x = coords[3*p], y = coords[3*p+1], z = coords[3*p+2];
        m = fmaxf(m, fmaf(x,x, fmaf(y,y, z*z)));
    }
    #pragma unroll
    for (int off = 32; off >= 1; off >>= 1)
        m = fmaxf(m, __shfl_down(m, off, 64));
    if ((t & 63) == 0) red[t >> 6] = m;
    for (int a = t; a < HSTRIDE * QG; a += 256) hist[a] = 0;
    __syncthreads();
    const float mm   = fmaxf(fmaxf(red[0], red[1]), fmaxf(red[2], red[3]));
    const float rmax = 2.0005f * sqrtf(mm) + 1e-3f;   // r_ij <= 2 max|c|
    const float h    = rmax / (float)QBINS;
    const float inv_h = 1.0f / h;

    // ---- histograms: load each j once, deposit into all ROWS rows ----
    const float* crow = coords + (size_t)b * N * 3;
    const unsigned char* mrow = mask + (size_t)b * N;
    const int il0 = i0 - b * N;            // local i of row 0

    float cx[ROWS], cy[ROWS], cz[ROWS];
    #pragma unroll
    for (int r = 0; r < ROWS; ++r) {
        cx[r] = crow[3*(il0+r)];
        cy[r] = crow[3*(il0+r)+1];
        cz[r] = crow[3*(il0+r)+2];
    }

    #pragma unroll
    for (int s = 0; s < N_FIXED / 256; ++s) {
        const int j = t + 256 * s;
        const float xj = crow[3*j], yj = crow[3*j+1], zj = crow[3*j+2];
        const bool masked = (mrow[j] != 0);
        #pragma unroll
        for (int r = 0; r < ROWS; ++r) {
            float dx = xj - cx[r];
            float dy = yj - cy[r];
            float dz = zj - cz[r];
            float d2 = fmaf(dx,dx, fmaf(dy,dy, fmaf(dz,dz, 1e-12f)));
            float rr = sqrtf(d2);
            float amp = 0.07957747154594767f / fmaxf(rr, 1e-6f);
            if (j == il0 + r || masked) amp = 0.0f;

            float u  = rr * inv_h;
            float qf = floorf(u);
            int   q0 = (int)qf;
            q0 = q0 < 0 ? 0 : (q0 > QBINS ? QBINS : q0);
            float tt = u - qf;
            // Lagrange cubic through nodes {-1,0,1,2} at offset tt in [0,1)
            float as  = amp * FPSCALE;
            float tm1 = tt + 1.0f, t1 = tt - 1.0f, t2 = tt - 2.0f;
            float w0 = -tt * t1 * t2 * (1.0f/6.0f) * as;
            float w1 =  tm1 * t1 * t2 * 0.5f * as;
            float w2 = -tm1 * tt * t2 * 0.5f * as;
            float w3 =  tm1 * tt * t1 * (1.0f/6.0f) * as;
            int* hb = &hist[q0 * HSTRIDE + r];
            atomicAdd(hb + 0*HSTRIDE, __float2int_rn(w0));  // native ds_add
            atomicAdd(hb + 1*HSTRIDE, __float2int_rn(w1));
            atomicAdd(hb + 2*HSTRIDE, __float2int_rn(w2));
            atomicAdd(hb + 3*HSTRIDE, __float2int_rn(w3));
        }
    }
    __syncthreads();

    // ---- convert int -> float in place (each slot touched by one thread) --
    float* hf = (float*)hist;
    const float invS = 1.0f / FPSCALE;
    for (int a = t; a < HSTRIDE * QG; a += 256) hf[a] = (float)hist[a] * invS;
    __syncthreads();

    // ---- in-block contraction: thread owns col-pair k=t for ALL 4 rows ----
    // step angle theta = wn_t * h; hw trans takes revolutions (<0.08 here)
    const float xrev = wavenumbers[t] * 0.15915494309189535f * h;
    const float cs = __builtin_amdgcn_cosf(xrev);
    const float sn = __builtin_amdgcn_sinf(xrev);
    float cr = cs, si = -sn;               // node q=0 is r=-h -> angle -theta
    float are[ROWS], aim[ROWS];
    #pragma unroll
    for (int r = 0; r < ROWS; ++r) { are[r] = 0.0f; aim[r] = 0.0f; }

    #pragma unroll 2
    for (int q = 0; q < QG; ++q) {
        const float* hq = hf + q * HSTRIDE;
        const float h0 = hq[0];            // same-address broadcast reads
        const float h1 = hq[1];
        const float h2 = hq[2];
        const float h3 = hq[3];
        are[0] = fmaf(h0, cr, are[0]); aim[0] = fmaf(h0, si, aim[0]);
        are[1] = fmaf(h1, cr, are[1]); aim[1] = fmaf(h1, si, aim[1]);
        are[2] = fmaf(h2, cr, are[2]); aim[2] = fmaf(h2, si, aim[2]);
        are[3] = fmaf(h3, cr, are[3]); aim[3] = fmaf(h3, si, aim[3]);
        const float cn = fmaf(cr, cs, -(si * sn));
        const float s2 = fmaf(si, cs,  (cr * sn));
        cr = cn; si = s2;
    }

    #pragma unroll
    for (int r = 0; r < ROWS; ++r)
        ((float2*)out)[(size_t)(i0 + r) * K_FIXED + t] = make_float2(are[r], aim[r]);
}

extern "C" void kernel_launch(void* const* d_in, const int* in_sizes, int n_in,
                              void* d_out, int out_size, void* d_ws, size_t ws_size,
                              hipStream_t stream) {
    const float* coords          = (const float*)d_in[0];
    const unsigned char* mask    = (const unsigned char*)d_in[1];
    const float* wavenumbers     = (const float*)d_in[2];
    float* out                   = (float*)d_out;

    const int K  = in_sizes[2];
    const int BN = in_sizes[0] / 3;        // B*N
    const int N  = N_FIXED;

    if (K != K_FIXED || BN % N != 0 || (N % ROWS) != 0) {
        wf_direct_kernel<<<BN, K, 0, stream>>>(coords, mask, wavenumbers, out, N, K);
        return;
    }

    wf_fused_kernel<<<BN / ROWS, 256, 0, stream>>>(coords, mask, wavenumbers,
                                                   out, BN, N);
}

// Round 8
// 78.583 us; speedup vs baseline: 1.3404x; 1.0649x over previous
//
#include <hip/hip_runtime.h>
#include <math.h>

// WavefunctionEmbedding, fully fused single kernel (NO workspace):
//   out[b,i,2k+0/1] = sum_j amp_ij * {cos,sin}(wn_k * r_ij)
// Block owns ROWS=4 rows: radial histograms in LDS (cubic Lagrange deposit,
// int32 fixed-point ds_add), then in-block contraction against
// cos/sin(wn_k * r_q) via per-thread rotation recurrence.
//
// R8 changes vs R7 (kernel ~37 us inferred; modeled floor ~15):
//  - hist r-major, row stride 272 floats (16B-aligned) -> contraction reads
//    4 q's per row with ONE ds_read_b128: 260 LDS instrs/wave vs 1040.
//  - 512-thread blocks; contraction q-range split across 2 teams
//    (0..131 / 132..259, team 1 seeded by hw cos/sin of 131*theta):
//    24 waves/CU (6/SIMD) vs 12 -> 2x latency hiding. 8 KB LDS merge.
//  - deposit math / h / rotation step bit-identical to R7.

#define N_FIXED  1536
#define K_FIXED  256
#define QBINS    256
#define QG       260            // node q represents r = (q-1)*h
#define ROWS     4              // rows per block (768 blocks)
#define RSTRIDE  272            // hist row stride in floats (16B-aligned)
#define NTHREADS 512
#define FPSCALE  4194304.0f     // 2^22 fixed-point scale for hist deposits

// ---------------- fallback: direct kernel (round-1, known-good) ------------
__global__ __launch_bounds__(256) void wf_direct_kernel(
    const float* __restrict__ coords, const unsigned char* __restrict__ mask,
    const float* __restrict__ wavenumbers, float* __restrict__ out, int N, int K)
{
    __shared__ float2 pairs[N_FIXED];
    const int row = blockIdx.x;
    const int b   = row / N;
    const int i   = row - b * N;
    const int t   = threadIdx.x;
    const float* crow = coords + (size_t)b * N * 3;
    const float xi = crow[i*3+0], yi = crow[i*3+1], zi = crow[i*3+2];
    const unsigned char* mrow = mask + (size_t)b * N;
    for (int j = t; j < N; j += blockDim.x) {
        float dx = crow[j*3+0]-xi, dy = crow[j*3+1]-yi, dz = crow[j*3+2]-zi;
        float d2 = fmaf(dx,dx, fmaf(dy,dy, fmaf(dz,dz, 1e-12f)));
        float r  = sqrtf(d2);
        float amp = 0.07957747154594767f / fmaxf(r, 1e-6f);
        if (j == i || mrow[j]) amp = 0.0f;
        pairs[j] = make_float2(r, amp);
    }
    __syncthreads();
    const int k = t;
    const float f = wavenumbers[k] * 0.15915494309189535f;
    float re = 0.0f, im = 0.0f;
    #pragma unroll 4
    for (int j = 0; j < N; ++j) {
        float2 p = pairs[j];
        float x  = __builtin_amdgcn_fractf(p.x * f);
        float c  = __builtin_amdgcn_cosf(x);
        float s  = __builtin_amdgcn_sinf(x);
        re = fmaf(c, p.y, re);
        im = fmaf(s, p.y, im);
    }
    float2* orow = (float2*)out + (size_t)row * K;
    orow[k] = make_float2(re, im);
}

// ---------------- fused: hist + in-block contraction -----------------------
__global__ __launch_bounds__(NTHREADS) void wf_fused_kernel(
    const float* __restrict__ coords, const unsigned char* __restrict__ mask,
    const float* __restrict__ wavenumbers, float* __restrict__ out,
    int n_pts, int N)
{
    __shared__ int    hist[ROWS * RSTRIDE];        // 4.25 KB, r-major
    __shared__ float  red[8];
    __shared__ float2 merge[ROWS * K_FIXED];       // 8 KB team-1 partials

    const int i0 = blockIdx.x * ROWS;      // first global row of this block
    const int b  = i0 / N;                 // N % ROWS == 0 -> block within b
    const int t  = threadIdx.x;

    // ---- redundant rmax over ALL points (identical in every block) ----
    float m = 0.0f;
    for (int p = t; p < n_pts; p += NTHREADS) {
        float x = coords[3*p], y = coords[3*p+1], z = coords[3*p+2];
        m = fmaxf(m, fmaf(x,x, fmaf(y,y, z*z)));
    }
    #pragma unroll
    for (int off = 32; off >= 1; off >>= 1)
        m = fmaxf(m, __shfl_down(m, off, 64));
    if ((t & 63) == 0) red[t >> 6] = m;
    for (int a = t; a < ROWS * RSTRIDE; a += NTHREADS) hist[a] = 0;
    __syncthreads();
    float mm = red[0];
    #pragma unroll
    for (int w = 1; w < 8; ++w) mm = fmaxf(mm, red[w]);
    const float rmax = 2.0005f * sqrtf(mm) + 1e-3f;   // r_ij <= 2 max|c|
    const float h    = rmax / (float)QBINS;
    const float inv_h = 1.0f / h;

    // ---- histograms: each j loaded once, deposit into all ROWS rows ----
    const float* crow = coords + (size_t)b * N * 3;
    const unsigned char* mrow = mask + (size_t)b * N;
    const int il0 = i0 - b * N;            // local i of row 0

    float cx[ROWS], cy[ROWS], cz[ROWS];
    #pragma unroll
    for (int r = 0; r < ROWS; ++r) {
        cx[r] = crow[3*(il0+r)];
        cy[r] = crow[3*(il0+r)+1];
        cz[r] = crow[3*(il0+r)+2];
    }

    #pragma unroll
    for (int s = 0; s < N_FIXED / NTHREADS; ++s) {
        const int j = t + NTHREADS * s;
        const float xj = crow[3*j], yj = crow[3*j+1], zj = crow[3*j+2];
        const bool masked = (mrow[j] != 0);
        #pragma unroll
        for (int r = 0; r < ROWS; ++r) {
            float dx = xj - cx[r];
            float dy = yj - cy[r];
            float dz = zj - cz[r];
            float d2 = fmaf(dx,dx, fmaf(dy,dy, fmaf(dz,dz, 1e-12f)));
            float rr = sqrtf(d2);
            float amp = 0.07957747154594767f / fmaxf(rr, 1e-6f);
            if (j == il0 + r || masked) amp = 0.0f;

            float u  = rr * inv_h;
            float qf = floorf(u);
            int   q0 = (int)qf;
            q0 = q0 < 0 ? 0 : (q0 > QBINS ? QBINS : q0);
            float tt = u - qf;
            // Lagrange cubic through nodes {-1,0,1,2} at offset tt in [0,1)
            float as  = amp * FPSCALE;
            float tm1 = tt + 1.0f, t1 = tt - 1.0f, t2 = tt - 2.0f;
            float w0 = -tt * t1 * t2 * (1.0f/6.0f) * as;
            float w1 =  tm1 * t1 * t2 * 0.5f * as;
            float w2 = -tm1 * tt * t2 * 0.5f * as;
            float w3 =  tm1 * tt * t1 * (1.0f/6.0f) * as;
            int* hb = &hist[r * RSTRIDE + q0];
            atomicAdd(hb + 0, __float2int_rn(w0));   // native ds_add
            atomicAdd(hb + 1, __float2int_rn(w1));
            atomicAdd(hb + 2, __float2int_rn(w2));
            atomicAdd(hb + 3, __float2int_rn(w3));
        }
    }
    __syncthreads();

    // ---- convert int -> float in place (each slot one thread) ----
    float* hf = (float*)hist;
    const float invS = 1.0f / FPSCALE;
    for (int a = t; a < ROWS * RSTRIDE; a += NTHREADS)
        hf[a] = (float)hist[a] * invS;
    __syncthreads();

    // ---- contraction: team = q-half, thread owns col-pair c for 4 rows ----
    const int team = t >> 8;               // 0 or 1
    const int c    = t & 255;              // col-pair index
    const int gbeg = team ? 33 : 0;        // groups of 4 q-nodes
    const int gend = team ? 65 : 33;       // 65 groups cover q 0..259
    const int qs   = gbeg * 4;

    const float xrev  = wavenumbers[c] * 0.15915494309189535f * h; // rev/node
    const float cstep = __builtin_amdgcn_cosf(__builtin_amdgcn_fractf(xrev));
    const float sstep = __builtin_amdgcn_sinf(__builtin_amdgcn_fractf(xrev));
    // seed z = cis((qs-1)*theta); node q has angle (q-1)*theta
    const float seed  = __builtin_amdgcn_fractf((float)(qs - 1) * xrev);
    float zr = __builtin_amdgcn_cosf(seed);
    float zi = __builtin_amdgcn_sinf(seed);

    float are[ROWS], aim[ROWS];
    #pragma unroll
    for (int r = 0; r < ROWS; ++r) { are[r] = 0.0f; aim[r] = 0.0f; }

    for (int g = gbeg; g < gend; ++g) {
        const int q0 = g * 4;
        const float4 h0 = *(const float4*)&hf[0 * RSTRIDE + q0]; // ds_read_b128
        const float4 h1 = *(const float4*)&hf[1 * RSTRIDE + q0];
        const float4 h2 = *(const float4*)&hf[2 * RSTRIDE + q0];
        const float4 h3 = *(const float4*)&hf[3 * RSTRIDE + q0];
        const float r0[4] = {h0.x, h0.y, h0.z, h0.w};
        const float r1[4] = {h1.x, h1.y, h1.z, h1.w};
        const float r2[4] = {h2.x, h2.y, h2.z, h2.w};
        const float r3[4] = {h3.x, h3.y, h3.z, h3.w};
        #pragma unroll
        for (int d = 0; d < 4; ++d) {
            are[0] = fmaf(r0[d], zr, are[0]); aim[0] = fmaf(r0[d], zi, aim[0]);
            are[1] = fmaf(r1[d], zr, are[1]); aim[1] = fmaf(r1[d], zi, aim[1]);
            are[2] = fmaf(r2[d], zr, are[2]); aim[2] = fmaf(r2[d], zi, aim[2]);
            are[3] = fmaf(r3[d], zr, are[3]); aim[3] = fmaf(r3[d], zi, aim[3]);
            const float zn  = fmaf(zr, cstep, -(zi * sstep));
            const float zni = fmaf(zi, cstep,  (zr * sstep));
            zr = zn; zi = zni;
        }
    }

    // ---- merge team 1 into team 0, store ----
    if (team == 1) {
        #pragma unroll
        for (int r = 0; r < ROWS; ++r)
            merge[r * K_FIXED + c] = make_float2(are[r], aim[r]);
    }
    __syncthreads();
    if (team == 0) {
        #pragma unroll
        for (int r = 0; r < ROWS; ++r) {
            const float2 p = merge[r * K_FIXED + c];
            ((float2*)out)[(size_t)(i0 + r) * K_FIXED + c] =
                make_float2(are[r] + p.x, aim[r] + p.y);
        }
    }
}

extern "C" void kernel_launch(void* const* d_in, const int* in_sizes, int n_in,
                              void* d_out, int out_size, void* d_ws, size_t ws_size,
                              hipStream_t stream) {
    const float* coords          = (const float*)d_in[0];
    const unsigned char* mask    = (const unsigned char*)d_in[1];
    const float* wavenumbers     = (const float*)d_in[2];
    float* out                   = (float*)d_out;

    const int K  = in_sizes[2];
    const int BN = in_sizes[0] / 3;        // B*N
    const int N  = N_FIXED;

    if (K != K_FIXED || BN % N != 0 || (N % ROWS) != 0 ||
        (N % NTHREADS) != 0) {
        wf_direct_kernel<<<BN, K, 0, stream>>>(coords, mask, wavenumbers, out, N, K);
        return;
    }

    wf_fused_kernel<<<BN / ROWS, NTHREADS, 0, stream>>>(coords, mask,
                                                        wavenumbers, out, BN, N);
}

// Round 9
// 75.370 us; speedup vs baseline: 1.3975x; 1.0426x over previous
//
#include <hip/hip_runtime.h>
#include <math.h>

// WavefunctionEmbedding, fully fused single kernel (NO workspace):
//   out[b,i,2k+0/1] = sum_j amp_ij * {cos,sin}(wn_k * r_ij)
// Block owns ROWS=4 rows of one batch: radial histograms in LDS (cubic
// Lagrange deposit, int32 fixed-point ds_add), then in-block contraction
// against cos/sin(wn_k * r_q) via per-thread Chebyshev recurrence.
//
// R9 (VALU-issue trim; kernel ~33 us, modeled floor ~12):
//  - contraction: rotation (4 FMA/q) -> Chebyshev 3-term (2 FMA/q):
//      w_{q+1} = 2cos(theta)*w_q - w_{q-1}   for cos and sin tracks.
//  - hist deposit: v_rsq replaces sqrt+max+IEEE-div (amp = C*rsq(d2),
//    u = d2*rsq*inv_h); clamps dropped (q0 in [0,255] provable from rmax
//    construction; r >= 1e-6 provable from +1e-12 floor); truncating int
//    casts (drop v_rndne; bias <= 1 ulp of 2^-22); shared weight products.
//  - rmax per-batch only (h need not be globally consistent: each block
//    deposits AND contracts with its own h).

#define N_FIXED  1536
#define K_FIXED  256
#define QBINS    256
#define QG       260            // node q represents r = (q-1)*h
#define ROWS     4              // rows per block (768 blocks = 3/CU)
#define RSTRIDE  272            // hist row stride in floats (16B-aligned)
#define NTHREADS 512
#define FPSCALE  4194304.0f     // 2^22 fixed-point scale for hist deposits

// ---------------- fallback: direct kernel (round-1, known-good) ------------
__global__ __launch_bounds__(256) void wf_direct_kernel(
    const float* __restrict__ coords, const unsigned char* __restrict__ mask,
    const float* __restrict__ wavenumbers, float* __restrict__ out, int N, int K)
{
    __shared__ float2 pairs[N_FIXED];
    const int row = blockIdx.x;
    const int b   = row / N;
    const int i   = row - b * N;
    const int t   = threadIdx.x;
    const float* crow = coords + (size_t)b * N * 3;
    const float xi = crow[i*3+0], yi = crow[i*3+1], zi = crow[i*3+2];
    const unsigned char* mrow = mask + (size_t)b * N;
    for (int j = t; j < N; j += blockDim.x) {
        float dx = crow[j*3+0]-xi, dy = crow[j*3+1]-yi, dz = crow[j*3+2]-zi;
        float d2 = fmaf(dx,dx, fmaf(dy,dy, fmaf(dz,dz, 1e-12f)));
        float r  = sqrtf(d2);
        float amp = 0.07957747154594767f / fmaxf(r, 1e-6f);
        if (j == i || mrow[j]) amp = 0.0f;
        pairs[j] = make_float2(r, amp);
    }
    __syncthreads();
    const int k = t;
    const float f = wavenumbers[k] * 0.15915494309189535f;
    float re = 0.0f, im = 0.0f;
    #pragma unroll 4
    for (int j = 0; j < N; ++j) {
        float2 p = pairs[j];
        float x  = __builtin_amdgcn_fractf(p.x * f);
        float c  = __builtin_amdgcn_cosf(x);
        float s  = __builtin_amdgcn_sinf(x);
        re = fmaf(c, p.y, re);
        im = fmaf(s, p.y, im);
    }
    float2* orow = (float2*)out + (size_t)row * K;
    orow[k] = make_float2(re, im);
}

// ---------------- fused: hist + in-block contraction -----------------------
__global__ __launch_bounds__(NTHREADS) void wf_fused_kernel(
    const float* __restrict__ coords, const unsigned char* __restrict__ mask,
    const float* __restrict__ wavenumbers, float* __restrict__ out, int N)
{
    __shared__ int    hist[ROWS * RSTRIDE];        // 4.25 KB, r-major
    __shared__ float  red[8];
    __shared__ float2 merge[ROWS * K_FIXED];       // 8 KB team-1 partials

    const int i0 = blockIdx.x * ROWS;      // first global row of this block
    const int b  = i0 / N;                 // N % ROWS == 0 -> block within b
    const int t  = threadIdx.x;

    const float* crow = coords + (size_t)b * N * 3;
    const unsigned char* mrow = mask + (size_t)b * N;

    // ---- rmax over THIS BATCH only (h is per-block-consistent) ----
    float m = 0.0f;
    #pragma unroll
    for (int s = 0; s < N_FIXED / NTHREADS; ++s) {
        const int p = t + NTHREADS * s;
        float x = crow[3*p], y = crow[3*p+1], z = crow[3*p+2];
        m = fmaxf(m, fmaf(x,x, fmaf(y,y, z*z)));
    }
    #pragma unroll
    for (int off = 32; off >= 1; off >>= 1)
        m = fmaxf(m, __shfl_down(m, off, 64));
    if ((t & 63) == 0) red[t >> 6] = m;
    for (int a = t; a < ROWS * RSTRIDE; a += NTHREADS) hist[a] = 0;
    __syncthreads();
    float mm = red[0];
    #pragma unroll
    for (int w = 1; w < 8; ++w) mm = fmaxf(mm, red[w]);
    const float rmax = 2.0005f * sqrtf(mm) + 1e-3f;   // r_ij <= 2 max|c|
    const float h    = rmax / (float)QBINS;           // => u = r/h < 256
    const float inv_h = 1.0f / h;

    // ---- histograms: each j loaded once, deposit into all ROWS rows ----
    const int il0 = i0 - b * N;            // local i of row 0
    float cx[ROWS], cy[ROWS], cz[ROWS];
    #pragma unroll
    for (int r = 0; r < ROWS; ++r) {
        cx[r] = crow[3*(il0+r)];
        cy[r] = crow[3*(il0+r)+1];
        cz[r] = crow[3*(il0+r)+2];
    }

    #pragma unroll
    for (int s = 0; s < N_FIXED / NTHREADS; ++s) {
        const int j = t + NTHREADS * s;
        const float xj = crow[3*j], yj = crow[3*j+1], zj = crow[3*j+2];
        const bool masked = (mrow[j] != 0);
        #pragma unroll
        for (int r = 0; r < ROWS; ++r) {
            float dx = xj - cx[r];
            float dy = yj - cy[r];
            float dz = zj - cz[r];
            float d2 = fmaf(dx,dx, fmaf(dy,dy, fmaf(dz,dz, 1e-12f)));
            float rsq = __builtin_amdgcn_rsqf(d2);     // 1/r, r >= 1e-6 always
            float amp = 0.07957747154594767f * rsq;    // 1/(4 pi r)
            if (j == il0 + r || masked) amp = 0.0f;

            float u  = d2 * rsq * inv_h;               // r/h, in [0,256)
            float qf = floorf(u);
            int   q0 = (int)qf;                        // 0..255, no clamp
            float tt = u - qf;
            // Lagrange cubic through nodes {-1,0,1,2} at offset tt in [0,1)
            float as6 = amp * (FPSCALE * (1.0f/6.0f));
            float as2 = amp * (FPSCALE * 0.5f);
            float tm1 = tt + 1.0f, t1 = tt - 1.0f, t2 = tt - 2.0f;
            float p  = tt  * t1;                       // t(t-1)
            float qq = tm1 * t2;                       // (t+1)(t-2)
            int w0 = (int)(-(p  * t2)  * as6);         // truncating cvt
            int w1 = (int)( (qq * t1)  * as2);
            int w2 = (int)(-(qq * tt)  * as2);
            int w3 = (int)( (p  * tm1) * as6);
            int* hb = &hist[r * RSTRIDE + q0];
            atomicAdd(hb + 0, w0);                     // native ds_add
            atomicAdd(hb + 1, w1);
            atomicAdd(hb + 2, w2);
            atomicAdd(hb + 3, w3);
        }
    }
    __syncthreads();

    // ---- convert int -> float in place (each slot one thread) ----
    float* hf = (float*)hist;
    const float invS = 1.0f / FPSCALE;
    for (int a = t; a < ROWS * RSTRIDE; a += NTHREADS)
        hf[a] = (float)hist[a] * invS;
    __syncthreads();

    // ---- contraction: team = q-half, thread owns col-pair c for 4 rows ----
    const int team = t >> 8;               // 0 or 1
    const int c    = t & 255;              // col-pair index
    const int gbeg = team ? 33 : 0;        // groups of 4 q-nodes
    const int gend = team ? 65 : 33;       // 65 groups cover q 0..259
    const int qs   = gbeg * 4;

    // theta (revolutions per node) = wn_c * h / 2pi; all args < ~10 rev
    const float xrev = wavenumbers[c] * 0.15915494309189535f * h;
    const float k2   = 2.0f * __builtin_amdgcn_cosf(__builtin_amdgcn_fractf(xrev));
    // Chebyshev seeds: z_a = cis((qs-1)*th), z_b = cis(qs*th)
    const float aarg = __builtin_amdgcn_fractf((float)(qs - 1) * xrev);
    const float barg = __builtin_amdgcn_fractf((float)qs * xrev);
    float ca = __builtin_amdgcn_cosf(aarg), sa = __builtin_amdgcn_sinf(aarg);
    float cb = __builtin_amdgcn_cosf(barg), sb = __builtin_amdgcn_sinf(barg);

    float are[ROWS], aim[ROWS];
    #pragma unroll
    for (int r = 0; r < ROWS; ++r) { are[r] = 0.0f; aim[r] = 0.0f; }

    #pragma unroll 2
    for (int g = gbeg; g < gend; ++g) {
        const int q0 = g * 4;
        const float4 h0 = *(const float4*)&hf[0 * RSTRIDE + q0]; // ds_read_b128
        const float4 h1 = *(const float4*)&hf[1 * RSTRIDE + q0];
        const float4 h2 = *(const float4*)&hf[2 * RSTRIDE + q0];
        const float4 h3 = *(const float4*)&hf[3 * RSTRIDE + q0];
        const float r0[4] = {h0.x, h0.y, h0.z, h0.w};
        const float r1[4] = {h1.x, h1.y, h1.z, h1.w};
        const float r2[4] = {h2.x, h2.y, h2.z, h2.w};
        const float r3[4] = {h3.x, h3.y, h3.z, h3.w};
        #pragma unroll
        for (int d = 0; d < 4; ++d) {
            are[0] = fmaf(r0[d], ca, are[0]); aim[0] = fmaf(r0[d], sa, aim[0]);
            are[1] = fmaf(r1[d], ca, are[1]); aim[1] = fmaf(r1[d], sa, aim[1]);
            are[2] = fmaf(r2[d], ca, are[2]); aim[2] = fmaf(r2[d], sa, aim[2]);
            are[3] = fmaf(r3[d], ca, are[3]); aim[3] = fmaf(r3[d], sa, aim[3]);
            const float cn = fmaf(k2, cb, -ca);        // Chebyshev step
            const float s2 = fmaf(k2, sb, -sa);
            ca = cb; cb = cn;
            sa = sb; sb = s2;
        }
    }

    // ---- merge team 1 into team 0, store ----
    if (team == 1) {
        #pragma unroll
        for (int r = 0; r < ROWS; ++r)
            merge[r * K_FIXED + c] = make_float2(are[r], aim[r]);
    }
    __syncthreads();
    if (team == 0) {
        #pragma unroll
        for (int r = 0; r < ROWS; ++r) {
            const float2 p = merge[r * K_FIXED + c];
            ((float2*)out)[(size_t)(i0 + r) * K_FIXED + c] =
                make_float2(are[r] + p.x, aim[r] + p.y);
        }
    }
}

extern "C" void kernel_launch(void* const* d_in, const int* in_sizes, int n_in,
                              void* d_out, int out_size, void* d_ws, size_t ws_size,
                              hipStream_t stream) {
    const float* coords          = (const float*)d_in[0];
    const unsigned char* mask    = (const unsigned char*)d_in[1];
    const float* wavenumbers     = (const float*)d_in[2];
    float* out                   = (float*)d_out;

    const int K  = in_sizes[2];
    const int BN = in_sizes[0] / 3;        // B*N
    const int N  = N_FIXED;

    if (K != K_FIXED || BN % N != 0 || (N % ROWS) != 0 ||
        (N % NTHREADS) != 0) {
        wf_direct_kernel<<<BN, K, 0, stream>>>(coords, mask, wavenumbers, out, N, K);
        return;
    }

    wf_fused_kernel<<<BN / ROWS, NTHREADS, 0, stream>>>(coords, mask,
                                                        wavenumbers, out, N);
}